// Round 1
// baseline (1487.362 us; speedup 1.0000x reference)
//
#include <hip/hip_runtime.h>

#define BDIM 256

// ---------------- reduction helper ----------------
__device__ __forceinline__ double block_reduce_sum(double v) {
#pragma unroll
    for (int off = 32; off > 0; off >>= 1)
        v += __shfl_down(v, off, 64);
    __shared__ double sh[BDIM / 64];
    const int lane = threadIdx.x & 63;
    const int wid  = threadIdx.x >> 6;
    if (lane == 0) sh[wid] = v;
    __syncthreads();
    double r = 0.0;
    if (wid == 0) {
        r = (lane < (BDIM / 64)) ? sh[lane] : 0.0;
#pragma unroll
        for (int off = BDIM / 128; off > 0; off >>= 1)
            r += __shfl_down(r, off, 64);
    }
    return r;  // valid in thread 0
}

// horizontal bilinear sample with zeros padding, align_corners=True.
// row points at src[b,c,j,0]; sample position x = ((i/(W-1)) + d) * (W-1)
__device__ __forceinline__ float warp_sample(const float* __restrict__ row,
                                             float d, int i, int W) {
    float xb = (float)i / (float)(W - 1);
    float gx = 2.0f * (xb + d) - 1.0f;
    float x  = (gx + 1.0f) * 0.5f * (float)(W - 1);
    float x0f = floorf(x);
    int   x0  = (int)x0f;
    float w1 = x - x0f;          // weight for x0+1
    float w0 = x0f + 1.0f - x;   // weight for x0
    float v = 0.0f;
    if (x0 >= 0 && x0 < W)           v += row[x0] * w0;
    if (x0 + 1 >= 0 && x0 + 1 < W)   v += row[x0 + 1] * w1;
    return v;
}

// ---------------- kernels ----------------
__global__ void zero_acc_kernel(double* acc) {
    if (threadIdx.x < 32) acc[threadIdx.x] = 0.0;
}

// generic align_corners bilinear resize; BC = B*C fused
__global__ void resize_kernel(const float* __restrict__ src, float* __restrict__ dst,
                              int BC, int Hs, int Ws, int Hd, int Wd) {
    long long idx = (long long)blockIdx.x * blockDim.x + threadIdx.x;
    long long total = (long long)BC * Hd * Wd;
    if (idx >= total) return;
    int i = (int)(idx % Wd);
    long long t = idx / Wd;
    int j = (int)(t % Hd);
    int bc = (int)(t / Hd);
    float stepy = (float)(Hs - 1) / (float)(Hd - 1);
    float stepx = (float)(Ws - 1) / (float)(Wd - 1);
    float y = j * stepy;
    float x = i * stepx;
    int y0 = (int)floorf(y);
    int y1 = min(y0 + 1, Hs - 1);
    int x0 = (int)floorf(x);
    int x1 = min(x0 + 1, Ws - 1);
    float wy = y - (float)y0;
    float wx = x - (float)x0;
    const float* s = src + (long long)bc * Hs * Ws;
    float t0 = s[(long long)y0 * Ws + x0] * (1.0f - wy) + s[(long long)y1 * Ws + x0] * wy;
    float t1 = s[(long long)y0 * Ws + x1] * (1.0f - wy) + s[(long long)y1 * Ws + x1] * wy;
    dst[idx] = t0 * (1.0f - wx) + t1 * wx;
}

// sum |x - warp(src, sign*disp)| over B*C*H*W
__global__ void l1_warp_kernel(const float* __restrict__ xp, long long xBS,
                               const float* __restrict__ sp, long long sBS,
                               const float* __restrict__ dp, long long dBS,
                               float sign, int B, int C, int H, int W,
                               double* acc) {
    const long long HW = (long long)H * W;
    const long long total = (long long)B * C * HW;
    double local = 0.0;
    for (long long idx = (long long)blockIdx.x * blockDim.x + threadIdx.x;
         idx < total; idx += (long long)gridDim.x * blockDim.x) {
        int i = (int)(idx % W);
        long long t = idx / W;
        int j = (int)(t % H); t /= H;
        int c = (int)(t % C);
        int b = (int)(t / C);
        float d = sign * dp[(long long)b * dBS + (long long)j * W + i];
        const float* srow = sp + (long long)b * sBS + (long long)c * HW + (long long)j * W;
        float yv = warp_sample(srow, d, i, W);
        float xv = xp[(long long)b * xBS + (long long)c * HW + (long long)j * W + i];
        local += (double)fabsf(xv - yv);
    }
    double bs = block_reduce_sum(local);
    if (threadIdx.x == 0) atomicAdd(acc, bs);
}

// sum of clip((1-SSIM)/2,0,1) over B*C*(H-2)*(W-2), y = warp(src, sign*disp) on the fly
__global__ void ssim_warp_kernel(const float* __restrict__ xp, long long xBS,
                                 const float* __restrict__ sp, long long sBS,
                                 const float* __restrict__ dp, long long dBS,
                                 float sign, int B, int C, int H, int W,
                                 double* acc) {
    const float C1v = 0.0001f;  // 0.01^2
    const float C2v = 0.0009f;  // 0.03^2
    const int Ho = H - 2, Wo = W - 2;
    const long long HW = (long long)H * W;
    const long long total = (long long)B * C * Ho * Wo;
    double local = 0.0;
    for (long long idx = (long long)blockIdx.x * blockDim.x + threadIdx.x;
         idx < total; idx += (long long)gridDim.x * blockDim.x) {
        int ii = (int)(idx % Wo);
        long long t = idx / Wo;
        int jj = (int)(t % Ho); t /= Ho;
        int c = (int)(t % C);
        int b = (int)(t / C);
        const float* xbase = xp + (long long)b * xBS + (long long)c * HW;
        const float* sbase = sp + (long long)b * sBS + (long long)c * HW;
        const float* dbase = dp + (long long)b * dBS;
        float Sx = 0.f, Sy = 0.f, Sxx = 0.f, Syy = 0.f, Sxy = 0.f;
#pragma unroll
        for (int ky = 0; ky < 3; ++ky) {
            int row = jj + ky;
            const float* xr = xbase + (long long)row * W;
            const float* sr = sbase + (long long)row * W;
            const float* drr = dbase + (long long)row * W;
#pragma unroll
            for (int kx = 0; kx < 3; ++kx) {
                int col = ii + kx;
                float xv = xr[col];
                float d  = sign * drr[col];
                float yv = warp_sample(sr, d, col, W);
                Sx += xv; Sy += yv;
                Sxx += xv * xv; Syy += yv * yv; Sxy += xv * yv;
            }
        }
        float mux = Sx / 9.0f, muy = Sy / 9.0f;
        float sigx = Sxx / 9.0f - mux * mux;
        float sigy = Syy / 9.0f - muy * muy;
        float cov  = Sxy / 9.0f - mux * muy;
        float num = (2.0f * mux * muy + C1v) * (2.0f * cov + C2v);
        float den = (mux * mux + muy * muy + C1v) * (sigx + sigy + C2v);
        float ssim = num / den;
        float v = (1.0f - ssim) * 0.5f;
        v = fminf(fmaxf(v, 0.0f), 1.0f);
        local += (double)v;
    }
    double bs = block_reduce_sum(local);
    if (threadIdx.x == 0) atomicAdd(acc, bs);
}

// sum over B*H*W of |x_grad(disp)*exp(-mean_c|x_grad(img)|)| + |y_grad(...)|
__global__ void smooth_kernel(const float* __restrict__ dp, long long dBS,
                              const float* __restrict__ ip, long long iBS,
                              int B, int H, int W, double* acc) {
    const long long HW = (long long)H * W;
    const long long total = (long long)B * HW;
    double local = 0.0;
    for (long long idx = (long long)blockIdx.x * blockDim.x + threadIdx.x;
         idx < total; idx += (long long)gridDim.x * blockDim.x) {
        int i = (int)(idx % W);
        long long t = idx / W;
        int j = (int)(t % H);
        int b = (int)(t / H);
        const float* db = dp + (long long)b * dBS;
        const float* ib = ip + (long long)b * iBS;
        float dv = db[(long long)j * W + i];
        float contrib = 0.0f;
        if (i < W - 1) {
            float s = 0.f;
#pragma unroll
            for (int c = 0; c < 3; ++c) {
                const float* r = ib + (long long)c * HW + (long long)j * W;
                s += fabsf(r[i] - r[i + 1]);
            }
            float wx = expf(-(s / 3.0f));
            float sx = (dv - db[(long long)j * W + i + 1]) * wx;
            contrib += fabsf(sx);
        }
        if (j < H - 1) {
            float s = 0.f;
#pragma unroll
            for (int c = 0; c < 3; ++c) {
                const float* r0 = ib + (long long)c * HW + (long long)j * W;
                const float* r1 = ib + (long long)c * HW + (long long)(j + 1) * W;
                s += fabsf(r0[i] - r1[i]);
            }
            float wy = expf(-(s / 3.0f));
            float sy = (dv - db[(long long)(j + 1) * W + i]) * wy;
            contrib += fabsf(sy);
        }
        local += (double)contrib;
    }
    double bs = block_reduce_sum(local);
    if (threadIdx.x == 0) atomicAdd(acc, bs);
}

__global__ void finalize_kernel(const double* __restrict__ acc, float* __restrict__ out) {
    const int B = 32, H0 = 256, W0 = 512;
    double AP = 0.0, LR = 0.0, DS = 0.0;
    for (int i = 0; i < 4; ++i) {
        int h = H0 >> i, w = W0 >> i;
        double nss = (double)B * 3.0 * (double)(h - 2) * (double)(w - 2);
        double nl1 = (double)B * 3.0 * (double)h * (double)w;
        double nd  = (double)B * (double)h * (double)w;
        AP += 0.85 * (acc[0 + i] / nss) + (1.0 - 0.85) * (acc[8 + i] / nl1);
        AP += 0.85 * (acc[4 + i] / nss) + (1.0 - 0.85) * (acc[12 + i] / nl1);
        LR += acc[16 + i] / nd + acc[20 + i] / nd;
        double sc = 1.0 / (double)(1 << i);
        DS += (acc[24 + i] / nd) * sc + (acc[28 + i] / nd) * sc;
    }
    AP *= 0.85;
    DS *= 0.1;
    double total = AP + LR + DS;
    out[0] = (float)total;
    out[1] = (float)AP;
    out[2] = (float)LR;
    out[3] = (float)DS;
}

// ---------------- host launch ----------------
static inline int grid_for(long long total) {
    long long b = (total + BDIM - 1) / BDIM;
    if (b > 2048) b = 2048;
    if (b < 1) b = 1;
    return (int)b;
}

extern "C" void kernel_launch(void* const* d_in, const int* in_sizes, int n_in,
                              void* d_out, int out_size, void* d_ws, size_t ws_size,
                              hipStream_t stream) {
    const int B = 32, H0 = 256, W0 = 512;
    const float* dsp[4];
    for (int i = 0; i < 4; ++i) dsp[i] = (const float*)d_in[i];
    const float* left  = (const float*)d_in[4];
    const float* right = (const float*)d_in[5];
    float* out = (float*)d_out;

    double* acc = (double*)d_ws;
    float* buf = (float*)((char*)d_ws + 256);

    const float* lp[4];
    const float* rp[4];
    float* lpm[4];
    float* rpm[4];
    lp[0] = left; rp[0] = right;
    float* cur = buf;
    for (int i = 1; i < 4; ++i) { lpm[i] = cur; cur += (long long)B * 3 * (H0 >> i) * (W0 >> i); }
    for (int i = 1; i < 4; ++i) { rpm[i] = cur; cur += (long long)B * 3 * (H0 >> i) * (W0 >> i); }
    for (int i = 1; i < 4; ++i) { lp[i] = lpm[i]; rp[i] = rpm[i]; }

    zero_acc_kernel<<<1, 64, 0, stream>>>(acc);

    // build pyramids (each level resized from the previous level)
    for (int i = 1; i < 4; ++i) {
        int Hs = H0 >> (i - 1), Ws = W0 >> (i - 1);
        int Hd = H0 >> i, Wd = W0 >> i;
        long long tot = (long long)B * 3 * Hd * Wd;
        int g = (int)((tot + BDIM - 1) / BDIM);
        resize_kernel<<<g, BDIM, 0, stream>>>(lp[i - 1], lpm[i], B * 3, Hs, Ws, Hd, Wd);
        resize_kernel<<<g, BDIM, 0, stream>>>(rp[i - 1], rpm[i], B * 3, Hs, Ws, Hd, Wd);
    }

    for (int i = 0; i < 4; ++i) {
        int h = H0 >> i, w = W0 >> i;
        long long HW = (long long)h * w;
        const float* dl = dsp[i];       // channel 0 of disp_i
        const float* dr = dsp[i] + HW;  // channel 1
        long long dBS = 2 * HW;         // per-batch stride of disp tensor
        long long iBS = 3 * HW;         // per-batch stride of image tensor

        long long tss = (long long)B * 3 * (h - 2) * (w - 2);
        ssim_warp_kernel<<<grid_for(tss), BDIM, 0, stream>>>(
            lp[i], iBS, rp[i], iBS, dl, dBS, -1.0f, B, 3, h, w, acc + 0 + i);
        ssim_warp_kernel<<<grid_for(tss), BDIM, 0, stream>>>(
            rp[i], iBS, lp[i], iBS, dr, dBS, +1.0f, B, 3, h, w, acc + 4 + i);

        long long tl1 = (long long)B * 3 * HW;
        l1_warp_kernel<<<grid_for(tl1), BDIM, 0, stream>>>(
            lp[i], iBS, rp[i], iBS, dl, dBS, -1.0f, B, 3, h, w, acc + 8 + i);
        l1_warp_kernel<<<grid_for(tl1), BDIM, 0, stream>>>(
            rp[i], iBS, lp[i], iBS, dr, dBS, +1.0f, B, 3, h, w, acc + 12 + i);

        long long tlr = (long long)B * HW;
        // |dl - warp(dr, -dl)|
        l1_warp_kernel<<<grid_for(tlr), BDIM, 0, stream>>>(
            dl, dBS, dr, dBS, dl, dBS, -1.0f, B, 1, h, w, acc + 16 + i);
        // |dr - warp(dl, dr)|
        l1_warp_kernel<<<grid_for(tlr), BDIM, 0, stream>>>(
            dr, dBS, dl, dBS, dr, dBS, +1.0f, B, 1, h, w, acc + 20 + i);

        smooth_kernel<<<grid_for(tlr), BDIM, 0, stream>>>(
            dl, dBS, lp[i], iBS, B, h, w, acc + 24 + i);
        smooth_kernel<<<grid_for(tlr), BDIM, 0, stream>>>(
            dr, dBS, rp[i], iBS, B, h, w, acc + 28 + i);
    }

    finalize_kernel<<<1, 1, 0, stream>>>(acc, out);
}

// Round 2
// 686.402 us; speedup vs baseline: 2.1669x; 2.1669x over previous
//
#include <hip/hip_runtime.h>

#define BDIM 256
#define TX 32
#define TY 8

// ---------------- reduction helper ----------------
// Safe to call repeatedly (syncs before reusing shared scratch).
__device__ __forceinline__ double block_reduce_sum(double v) {
    __shared__ double sh[BDIM / 64];
#pragma unroll
    for (int off = 32; off > 0; off >>= 1)
        v += __shfl_down(v, off, 64);
    const int lane = threadIdx.x & 63;
    const int wid  = threadIdx.x >> 6;
    __syncthreads();
    if (lane == 0) sh[wid] = v;
    __syncthreads();
    double r = 0.0;
    if (wid == 0) {
        r = (lane < (BDIM / 64)) ? sh[lane] : 0.0;
#pragma unroll
        for (int off = BDIM / 128; off > 0; off >>= 1)
            r += __shfl_down(r, off, 64);
    }
    return r;  // valid in thread 0
}

// ---------------- kernels ----------------
__global__ void zero_acc_kernel(double* acc) {
    if (threadIdx.x < 32) acc[threadIdx.x] = 0.0;
}

// generic align_corners bilinear resize; BC = B*C fused
__global__ void resize_kernel(const float* __restrict__ src, float* __restrict__ dst,
                              int BC, int Hs, int Ws, int Hd, int Wd) {
    long long idx = (long long)blockIdx.x * blockDim.x + threadIdx.x;
    long long total = (long long)BC * Hd * Wd;
    if (idx >= total) return;
    int i = (int)(idx % Wd);
    long long t = idx / Wd;
    int j = (int)(t % Hd);
    int bc = (int)(t / Hd);
    float stepy = (float)(Hs - 1) / (float)(Hd - 1);
    float stepx = (float)(Ws - 1) / (float)(Wd - 1);
    float y = j * stepy;
    float x = i * stepx;
    int y0 = (int)floorf(y);
    int y1 = min(y0 + 1, Hs - 1);
    int x0 = (int)floorf(x);
    int x1 = min(x0 + 1, Ws - 1);
    float wy = y - (float)y0;
    float wx = x - (float)x0;
    const float* s = src + (long long)bc * Hs * Ws;
    float t0 = s[(long long)y0 * Ws + x0] * (1.0f - wy) + s[(long long)y1 * Ws + x0] * wy;
    float t1 = s[(long long)y0 * Ws + x1] * (1.0f - wy) + s[(long long)y1 * Ws + x1] * wy;
    dst[idx] = t0 * (1.0f - wx) + t1 * wx;
}

// Fused SSIM + L1 over one side.
// Tiles of TX x TY outputs; input tile (TX+2)x(TY+2) per channel.
// Warp position computed once per input pixel, reused across 3 channels.
// L1 accumulated over "owned" input pixels (each pixel owned by exactly one tile).
__global__ void __launch_bounds__(BDIM)
ssim_l1_kernel(const float* __restrict__ xp, const float* __restrict__ sp,
               const float* __restrict__ dp,
               long long iBS, long long dBS, float sign,
               int B, int H, int W, int nTx, int nTy,
               double* __restrict__ accS, double* __restrict__ accL) {
    __shared__ float xs[3][TY + 2][TX + 2];
    __shared__ float ys[3][TY + 2][TX + 2];
    const float C1v = 0.0001f;
    const float C2v = 0.0009f;
    const long long HW = (long long)H * W;
    const float Wm1 = (float)(W - 1);
    const int numTiles = B * nTx * nTy;
    double sS = 0.0, sL = 0.0;

    for (int tile = blockIdx.x; tile < numTiles; tile += gridDim.x) {
        int tx = tile % nTx;
        int t2 = tile / nTx;
        int ty = t2 % nTy;
        int b  = t2 / nTy;
        int ox = tx * TX, oy = ty * TY;
        const float* xb = xp + (long long)b * iBS;
        const float* sb = sp + (long long)b * iBS;
        const float* db = dp + (long long)b * dBS;

        __syncthreads();  // previous tile's LDS reads done
        for (int t = threadIdx.x; t < (TY + 2) * (TX + 2); t += BDIM) {
            int ly = t / (TX + 2), lx = t % (TX + 2);
            int row = oy + ly, col = ox + lx;
            if (row < H && col < W) {
                float d   = sign * db[(long long)row * W + col];
                float x   = fmaf(d, Wm1, (float)col);
                float x0f = floorf(x);
                int   x0  = (int)x0f;
                float w1  = x - x0f;
                float w0  = 1.0f - w1;
                bool in0 = (x0 >= 0) && (x0 < W);
                bool in1 = (x0 >= -1) && (x0 < W - 1);
                bool own = (lx < TX || tx == nTx - 1) && (ly < TY || ty == nTy - 1);
                const long long roff = (long long)row * W;
#pragma unroll
                for (int c = 0; c < 3; ++c) {
                    const float* xr = xb + (long long)c * HW + roff;
                    const float* sr = sb + (long long)c * HW + roff;
                    float xv = xr[col];
                    float yv = 0.0f;
                    if (in0) yv += sr[x0] * w0;
                    if (in1) yv += sr[x0 + 1] * w1;
                    xs[c][ly][lx] = xv;
                    ys[c][ly][lx] = yv;
                    if (own) sL += (double)fabsf(xv - yv);
                }
            } else {
#pragma unroll
                for (int c = 0; c < 3; ++c) { xs[c][ly][lx] = 0.0f; ys[c][ly][lx] = 0.0f; }
            }
        }
        __syncthreads();

        for (int t = threadIdx.x; t < 3 * TY * TX; t += BDIM) {
            int c = t / (TY * TX);
            int r = t % (TY * TX);
            int ly = r / TX, lx = r % TX;
            int jj = oy + ly, ii = ox + lx;
            if (jj < H - 2 && ii < W - 2) {
                float Sx = 0.f, Sy = 0.f, Sxx = 0.f, Syy = 0.f, Sxy = 0.f;
#pragma unroll
                for (int ky = 0; ky < 3; ++ky) {
#pragma unroll
                    for (int kx = 0; kx < 3; ++kx) {
                        float xv = xs[c][ly + ky][lx + kx];
                        float yv = ys[c][ly + ky][lx + kx];
                        Sx += xv; Sy += yv;
                        Sxx = fmaf(xv, xv, Sxx);
                        Syy = fmaf(yv, yv, Syy);
                        Sxy = fmaf(xv, yv, Sxy);
                    }
                }
                float mux = Sx * (1.0f / 9.0f), muy = Sy * (1.0f / 9.0f);
                float sigx = Sxx * (1.0f / 9.0f) - mux * mux;
                float sigy = Syy * (1.0f / 9.0f) - muy * muy;
                float cov  = Sxy * (1.0f / 9.0f) - mux * muy;
                float num = (2.0f * mux * muy + C1v) * (2.0f * cov + C2v);
                float den = (mux * mux + muy * muy + C1v) * (sigx + sigy + C2v);
                float v = (1.0f - num / den) * 0.5f;
                v = fminf(fmaxf(v, 0.0f), 1.0f);
                sS += (double)v;
            }
        }
    }

    double r = block_reduce_sum(sS);
    if (threadIdx.x == 0) atomicAdd(accS, r);
    r = block_reduce_sum(sL);
    if (threadIdx.x == 0) atomicAdd(accL, r);
}

// Fused LR-consistency (both directions) + smoothness (both disparities) per level.
// acc layout offsets: +0 lr_l, +4 lr_r, +8 ds_l, +12 ds_r  (relative to acc+16+i)
__global__ void __launch_bounds__(BDIM)
disp_kernel(const float* __restrict__ d0, const float* __restrict__ lp,
            const float* __restrict__ rp, long long dBS, long long iBS,
            int B, int H, int W, double* __restrict__ acc) {
    const long long HW = (long long)H * W;
    const long long total = (long long)B * HW;
    const float Wm1 = (float)(W - 1);
    double sLRl = 0.0, sLRr = 0.0, sDSl = 0.0, sDSr = 0.0;

    for (long long idx = (long long)blockIdx.x * blockDim.x + threadIdx.x;
         idx < total; idx += (long long)gridDim.x * blockDim.x) {
        int i = (int)(idx % W);
        long long t = idx / W;
        int j = (int)(t % H);
        int b = (int)(t / H);
        const float* dlb = d0 + (long long)b * dBS;        // ch0
        const float* drb = d0 + (long long)b * dBS + HW;   // ch1
        const long long roff = (long long)j * W;
        float dl = dlb[roff + i];
        float dr = drb[roff + i];

        // LR: |dl - warp(dr, -dl)|
        {
            float x   = fmaf(-dl, Wm1, (float)i);
            float x0f = floorf(x);
            int   x0  = (int)x0f;
            float w1  = x - x0f, w0 = 1.0f - w1;
            float v = 0.0f;
            if (x0 >= 0 && x0 < W)       v += drb[roff + x0] * w0;
            if (x0 >= -1 && x0 < W - 1)  v += drb[roff + x0 + 1] * w1;
            sLRl += (double)fabsf(dl - v);
        }
        // LR: |dr - warp(dl, +dr)|
        {
            float x   = fmaf(dr, Wm1, (float)i);
            float x0f = floorf(x);
            int   x0  = (int)x0f;
            float w1  = x - x0f, w0 = 1.0f - w1;
            float v = 0.0f;
            if (x0 >= 0 && x0 < W)       v += dlb[roff + x0] * w0;
            if (x0 >= -1 && x0 < W - 1)  v += dlb[roff + x0 + 1] * w1;
            sLRr += (double)fabsf(dr - v);
        }
        // Smoothness
        const float* lb = lp + (long long)b * iBS;
        const float* rb = rp + (long long)b * iBS;
        if (i < W - 1) {
            float sl = 0.f, sr2 = 0.f;
#pragma unroll
            for (int c = 0; c < 3; ++c) {
                const float* l = lb + (long long)c * HW + roff;
                const float* r = rb + (long long)c * HW + roff;
                sl  += fabsf(l[i] - l[i + 1]);
                sr2 += fabsf(r[i] - r[i + 1]);
            }
            sDSl += (double)fabsf((dl - dlb[roff + i + 1]) * expf(-(sl * (1.0f / 3.0f))));
            sDSr += (double)fabsf((dr - drb[roff + i + 1]) * expf(-(sr2 * (1.0f / 3.0f))));
        }
        if (j < H - 1) {
            float sl = 0.f, sr2 = 0.f;
#pragma unroll
            for (int c = 0; c < 3; ++c) {
                const float* l0 = lb + (long long)c * HW + roff;
                const float* r0 = rb + (long long)c * HW + roff;
                sl  += fabsf(l0[i] - l0[i + W]);
                sr2 += fabsf(r0[i] - r0[i + W]);
            }
            sDSl += (double)fabsf((dl - dlb[roff + W + i]) * expf(-(sl * (1.0f / 3.0f))));
            sDSr += (double)fabsf((dr - drb[roff + W + i]) * expf(-(sr2 * (1.0f / 3.0f))));
        }
    }

    double r;
    r = block_reduce_sum(sLRl); if (threadIdx.x == 0) atomicAdd(acc + 0,  r);
    r = block_reduce_sum(sLRr); if (threadIdx.x == 0) atomicAdd(acc + 4,  r);
    r = block_reduce_sum(sDSl); if (threadIdx.x == 0) atomicAdd(acc + 8,  r);
    r = block_reduce_sum(sDSr); if (threadIdx.x == 0) atomicAdd(acc + 12, r);
}

__global__ void finalize_kernel(const double* __restrict__ acc, float* __restrict__ out) {
    const int B = 32, H0 = 256, W0 = 512;
    double AP = 0.0, LR = 0.0, DS = 0.0;
    for (int i = 0; i < 4; ++i) {
        int h = H0 >> i, w = W0 >> i;
        double nss = (double)B * 3.0 * (double)(h - 2) * (double)(w - 2);
        double nl1 = (double)B * 3.0 * (double)h * (double)w;
        double nd  = (double)B * (double)h * (double)w;
        AP += 0.85 * (acc[0 + i] / nss) + 0.15 * (acc[8 + i] / nl1);
        AP += 0.85 * (acc[4 + i] / nss) + 0.15 * (acc[12 + i] / nl1);
        LR += acc[16 + i] / nd + acc[20 + i] / nd;
        double sc = 1.0 / (double)(1 << i);
        DS += (acc[24 + i] / nd) * sc + (acc[28 + i] / nd) * sc;
    }
    AP *= 0.85;
    DS *= 0.1;
    double total = AP + LR + DS;
    out[0] = (float)total;
    out[1] = (float)AP;
    out[2] = (float)LR;
    out[3] = (float)DS;
}

// ---------------- host launch ----------------
static inline int grid_cap(long long blocks) {
    if (blocks > 2048) blocks = 2048;
    if (blocks < 1) blocks = 1;
    return (int)blocks;
}

extern "C" void kernel_launch(void* const* d_in, const int* in_sizes, int n_in,
                              void* d_out, int out_size, void* d_ws, size_t ws_size,
                              hipStream_t stream) {
    const int B = 32, H0 = 256, W0 = 512;
    const float* dsp[4];
    for (int i = 0; i < 4; ++i) dsp[i] = (const float*)d_in[i];
    const float* left  = (const float*)d_in[4];
    const float* right = (const float*)d_in[5];
    float* out = (float*)d_out;

    double* acc = (double*)d_ws;
    float* buf = (float*)((char*)d_ws + 256);

    const float* lp[4];
    const float* rp[4];
    float* lpm[4];
    float* rpm[4];
    lp[0] = left; rp[0] = right;
    float* cur = buf;
    for (int i = 1; i < 4; ++i) { lpm[i] = cur; cur += (long long)B * 3 * (H0 >> i) * (W0 >> i); }
    for (int i = 1; i < 4; ++i) { rpm[i] = cur; cur += (long long)B * 3 * (H0 >> i) * (W0 >> i); }
    for (int i = 1; i < 4; ++i) { lp[i] = lpm[i]; rp[i] = rpm[i]; }

    zero_acc_kernel<<<1, 64, 0, stream>>>(acc);

    for (int i = 1; i < 4; ++i) {
        int Hs = H0 >> (i - 1), Ws = W0 >> (i - 1);
        int Hd = H0 >> i, Wd = W0 >> i;
        long long tot = (long long)B * 3 * Hd * Wd;
        int g = (int)((tot + BDIM - 1) / BDIM);
        resize_kernel<<<g, BDIM, 0, stream>>>(lp[i - 1], lpm[i], B * 3, Hs, Ws, Hd, Wd);
        resize_kernel<<<g, BDIM, 0, stream>>>(rp[i - 1], rpm[i], B * 3, Hs, Ws, Hd, Wd);
    }

    for (int i = 0; i < 4; ++i) {
        int h = H0 >> i, w = W0 >> i;
        long long HW = (long long)h * w;
        const float* dl = dsp[i];       // channel 0
        long long dBS = 2 * HW;
        long long iBS = 3 * HW;

        int nTx = (w - 2 + TX - 1) / TX;
        int nTy = (h - 2 + TY - 1) / TY;
        int numTiles = B * nTx * nTy;
        int g = grid_cap(numTiles);

        // left_est: x = left pyr, src = right pyr, disp = dl, sign = -1
        ssim_l1_kernel<<<g, BDIM, 0, stream>>>(
            lp[i], rp[i], dl, iBS, dBS, -1.0f, B, h, w, nTx, nTy,
            acc + 0 + i, acc + 8 + i);
        // right_est: x = right pyr, src = left pyr, disp = dr (= dl + HW), sign = +1
        ssim_l1_kernel<<<g, BDIM, 0, stream>>>(
            rp[i], lp[i], dl + HW, iBS, dBS, +1.0f, B, h, w, nTx, nTy,
            acc + 4 + i, acc + 12 + i);

        long long tot = (long long)B * HW;
        disp_kernel<<<grid_cap((tot + BDIM - 1) / BDIM), BDIM, 0, stream>>>(
            dsp[i], lp[i], rp[i], dBS, iBS, B, h, w, acc + 16 + i);
    }

    finalize_kernel<<<1, 1, 0, stream>>>(acc, out);
}

// Round 3
// 625.818 us; speedup vs baseline: 2.3767x; 1.0968x over previous
//
#include <hip/hip_runtime.h>

#define BDIM 256
#define TX 32
#define TY 8

// ---------------- reduction helper ----------------
__device__ __forceinline__ double block_reduce_sum(double v) {
    __shared__ double sh[BDIM / 64];
#pragma unroll
    for (int off = 32; off > 0; off >>= 1)
        v += __shfl_down(v, off, 64);
    const int lane = threadIdx.x & 63;
    const int wid  = threadIdx.x >> 6;
    __syncthreads();
    if (lane == 0) sh[wid] = v;
    __syncthreads();
    double r = 0.0;
    if (wid == 0) {
        r = (lane < (BDIM / 64)) ? sh[lane] : 0.0;
#pragma unroll
        for (int off = BDIM / 128; off > 0; off >>= 1)
            r += __shfl_down(r, off, 64);
    }
    return r;  // valid in thread 0
}

// ---------------- kernels ----------------
__global__ void zero_acc_kernel(double* acc) {
    if (threadIdx.x < 32) acc[threadIdx.x] = 0.0;
}

// generic align_corners bilinear resize; BC = B*C fused
__global__ void resize_kernel(const float* __restrict__ src, float* __restrict__ dst,
                              int BC, int Hs, int Ws, int Hd, int Wd) {
    long long idx = (long long)blockIdx.x * blockDim.x + threadIdx.x;
    long long total = (long long)BC * Hd * Wd;
    if (idx >= total) return;
    int i = (int)(idx % Wd);
    long long t = idx / Wd;
    int j = (int)(t % Hd);
    int bc = (int)(t / Hd);
    float stepy = (float)(Hs - 1) / (float)(Hd - 1);
    float stepx = (float)(Ws - 1) / (float)(Wd - 1);
    float y = j * stepy;
    float x = i * stepx;
    int y0 = (int)floorf(y);
    int y1 = min(y0 + 1, Hs - 1);
    int x0 = (int)floorf(x);
    int x1 = min(x0 + 1, Ws - 1);
    float wy = y - (float)y0;
    float wx = x - (float)x0;
    const float* s = src + (long long)bc * Hs * Ws;
    float t0 = s[(long long)y0 * Ws + x0] * (1.0f - wy) + s[(long long)y1 * Ws + x0] * wy;
    float t1 = s[(long long)y0 * Ws + x1] * (1.0f - wy) + s[(long long)y1 * Ws + x1] * wy;
    dst[idx] = t0 * (1.0f - wx) + t1 * wx;
}

__device__ __forceinline__ float ssim_term(float Sx, float Sy, float Sxx, float Syy, float Sxy) {
    const float C1v = 0.0001f;
    const float C2v = 0.0009f;
    float mux = Sx * (1.0f / 9.0f), muy = Sy * (1.0f / 9.0f);
    float sigx = Sxx * (1.0f / 9.0f) - mux * mux;
    float sigy = Syy * (1.0f / 9.0f) - muy * muy;
    float cov  = Sxy * (1.0f / 9.0f) - mux * muy;
    float num = (2.0f * mux * muy + C1v) * (2.0f * cov + C2v);
    float den = (mux * mux + muy * muy + C1v) * (sigx + sigy + C2v);
    float v = (1.0f - num / den) * 0.5f;
    return fminf(fmaxf(v, 0.0f), 1.0f);
}

// One kernel per pyramid level: SSIM(l,r) + L1(l,r) + LR(l,r) + smooth(l,r).
// acc slot layout (stride 4 between terms, host passes acc+level):
//  +0 ssim_l, +4 ssim_r, +8 l1_l, +12 l1_r, +16 lr_l, +20 lr_r, +24 ds_l, +28 ds_r
__global__ void __launch_bounds__(BDIM)
fused_level_kernel(const float* __restrict__ lp, const float* __restrict__ rp,
                   const float* __restrict__ dp,
                   long long iBS, long long dBS,
                   int B, int H, int W, int nTx, int nTy,
                   double* __restrict__ acc) {
    __shared__ float ls[3][TY + 2][TX + 2];
    __shared__ float rs[3][TY + 2][TX + 2];
    __shared__ float les[3][TY + 2][TX + 2];
    __shared__ float res[3][TY + 2][TX + 2];
    __shared__ float dls[TY + 2][TX + 2];
    __shared__ float drs[TY + 2][TX + 2];

    const long long HW = (long long)H * W;
    const float Wm1 = (float)(W - 1);
    const int numTiles = B * nTx * nTy;

    double sSl = 0.0, sSr = 0.0, sLl = 0.0, sLr = 0.0;
    double sRl = 0.0, sRr = 0.0, sDl = 0.0, sDr = 0.0;

    for (int tile = blockIdx.x; tile < numTiles; tile += gridDim.x) {
        int tx = tile % nTx;
        int t2 = tile / nTx;
        int ty = t2 % nTy;
        int b  = t2 / nTy;
        int ox = tx * TX, oy = ty * TY;
        const float* lb = lp + (long long)b * iBS;
        const float* rb = rp + (long long)b * iBS;
        const float* db = dp + (long long)b * dBS;

        __syncthreads();  // previous tile's LDS reads complete

        // ---- Phase 1: stage tile, compute warps once, accumulate L1 + LR ----
        for (int t = threadIdx.x; t < (TY + 2) * (TX + 2); t += BDIM) {
            int ly = t / (TX + 2), lx = t % (TX + 2);
            int row = oy + ly, col = ox + lx;
            if (row < H && col < W) {
                const long long roff = (long long)row * W;
                const float* dlrow = db + roff;
                const float* drrow = db + HW + roff;
                float dl = dlrow[col];
                float dr = drrow[col];
                dls[ly][lx] = dl;
                drs[ly][lx] = dr;

                // left-est sample position (sign -1 on dl)
                float xl = fmaf(-dl, Wm1, (float)col);
                float xlf = floorf(xl);
                int   x0l = (int)xlf;
                float w1l = xl - xlf, w0l = 1.0f - w1l;
                bool la = (x0l >= 0) && (x0l < W);
                bool lb2 = (x0l >= -1) && (x0l < W - 1);
                // right-est sample position (sign +1 on dr)
                float xr = fmaf(dr, Wm1, (float)col);
                float xrf = floorf(xr);
                int   x0r = (int)xrf;
                float w1r = xr - xrf, w0r = 1.0f - w1r;
                bool ra = (x0r >= 0) && (x0r < W);
                bool rb2 = (x0r >= -1) && (x0r < W - 1);

                bool own = (lx < TX || tx == nTx - 1) && (ly < TY || ty == nTy - 1);

#pragma unroll
                for (int c = 0; c < 3; ++c) {
                    const float* lrow = lb + (long long)c * HW + roff;
                    const float* rrow = rb + (long long)c * HW + roff;
                    float lv = lrow[col];
                    float rv = rrow[col];
                    float le = 0.0f, re = 0.0f;
                    if (la)  le += rrow[x0l] * w0l;
                    if (lb2) le += rrow[x0l + 1] * w1l;
                    if (ra)  re += lrow[x0r] * w0r;
                    if (rb2) re += lrow[x0r + 1] * w1r;
                    ls[c][ly][lx] = lv;
                    rs[c][ly][lx] = rv;
                    les[c][ly][lx] = le;
                    res[c][ly][lx] = re;
                    if (own) {
                        sLl += (double)fabsf(lv - le);
                        sLr += (double)fabsf(rv - re);
                    }
                }
                if (own) {
                    float wl = 0.0f, wr = 0.0f;
                    if (la)  wl += drrow[x0l] * w0l;
                    if (lb2) wl += drrow[x0l + 1] * w1l;
                    if (ra)  wr += dlrow[x0r] * w0r;
                    if (rb2) wr += dlrow[x0r + 1] * w1r;
                    sRl += (double)fabsf(dl - wl);
                    sRr += (double)fabsf(dr - wr);
                }
            } else {
#pragma unroll
                for (int c = 0; c < 3; ++c) {
                    ls[c][ly][lx] = 0.0f; rs[c][ly][lx] = 0.0f;
                    les[c][ly][lx] = 0.0f; res[c][ly][lx] = 0.0f;
                }
                dls[ly][lx] = 0.0f; drs[ly][lx] = 0.0f;
            }
        }
        __syncthreads();

        // ---- Phase 1.5: smoothness from LDS ----
        for (int t = threadIdx.x; t < (TY + 2) * (TX + 2); t += BDIM) {
            int ly = t / (TX + 2), lx = t % (TX + 2);
            int row = oy + ly, col = ox + lx;
            bool own = (lx < TX || tx == nTx - 1) && (ly < TY || ty == nTy - 1);
            if (row < H && col < W && own) {
                float dl = dls[ly][lx], dr = drs[ly][lx];
                if (col < W - 1) {
                    float sl = 0.f, sr2 = 0.f;
#pragma unroll
                    for (int c = 0; c < 3; ++c) {
                        sl  += fabsf(ls[c][ly][lx] - ls[c][ly][lx + 1]);
                        sr2 += fabsf(rs[c][ly][lx] - rs[c][ly][lx + 1]);
                    }
                    sDl += (double)fabsf((dl - dls[ly][lx + 1]) * expf(-(sl * (1.0f / 3.0f))));
                    sDr += (double)fabsf((dr - drs[ly][lx + 1]) * expf(-(sr2 * (1.0f / 3.0f))));
                }
                if (row < H - 1) {
                    float sl = 0.f, sr2 = 0.f;
#pragma unroll
                    for (int c = 0; c < 3; ++c) {
                        sl  += fabsf(ls[c][ly][lx] - ls[c][ly + 1][lx]);
                        sr2 += fabsf(rs[c][ly][lx] - rs[c][ly + 1][lx]);
                    }
                    sDl += (double)fabsf((dl - dls[ly + 1][lx]) * expf(-(sl * (1.0f / 3.0f))));
                    sDr += (double)fabsf((dr - drs[ly + 1][lx]) * expf(-(sr2 * (1.0f / 3.0f))));
                }
            }
        }

        // ---- Phase 2: SSIM both directions from LDS ----
        for (int t = threadIdx.x; t < 3 * TY * TX; t += BDIM) {
            int c = t / (TY * TX);
            int r = t % (TY * TX);
            int ly = r / TX, lx = r % TX;
            int jj = oy + ly, ii = ox + lx;
            if (jj < H - 2 && ii < W - 2) {
                float lSx = 0.f, lSy = 0.f, lSxx = 0.f, lSyy = 0.f, lSxy = 0.f;
                float rSx = 0.f, rSy = 0.f, rSxx = 0.f, rSyy = 0.f, rSxy = 0.f;
#pragma unroll
                for (int ky = 0; ky < 3; ++ky) {
#pragma unroll
                    for (int kx = 0; kx < 3; ++kx) {
                        float xv = ls[c][ly + ky][lx + kx];
                        float yv = les[c][ly + ky][lx + kx];
                        lSx += xv; lSy += yv;
                        lSxx = fmaf(xv, xv, lSxx);
                        lSyy = fmaf(yv, yv, lSyy);
                        lSxy = fmaf(xv, yv, lSxy);
                        float xv2 = rs[c][ly + ky][lx + kx];
                        float yv2 = res[c][ly + ky][lx + kx];
                        rSx += xv2; rSy += yv2;
                        rSxx = fmaf(xv2, xv2, rSxx);
                        rSyy = fmaf(yv2, yv2, rSyy);
                        rSxy = fmaf(xv2, yv2, rSxy);
                    }
                }
                sSl += (double)ssim_term(lSx, lSy, lSxx, lSyy, lSxy);
                sSr += (double)ssim_term(rSx, rSy, rSxx, rSyy, rSxy);
            }
        }
    }

    double r;
    r = block_reduce_sum(sSl); if (threadIdx.x == 0) atomicAdd(acc + 0,  r);
    r = block_reduce_sum(sSr); if (threadIdx.x == 0) atomicAdd(acc + 4,  r);
    r = block_reduce_sum(sLl); if (threadIdx.x == 0) atomicAdd(acc + 8,  r);
    r = block_reduce_sum(sLr); if (threadIdx.x == 0) atomicAdd(acc + 12, r);
    r = block_reduce_sum(sRl); if (threadIdx.x == 0) atomicAdd(acc + 16, r);
    r = block_reduce_sum(sRr); if (threadIdx.x == 0) atomicAdd(acc + 20, r);
    r = block_reduce_sum(sDl); if (threadIdx.x == 0) atomicAdd(acc + 24, r);
    r = block_reduce_sum(sDr); if (threadIdx.x == 0) atomicAdd(acc + 28, r);
}

__global__ void finalize_kernel(const double* __restrict__ acc, float* __restrict__ out) {
    const int B = 32, H0 = 256, W0 = 512;
    double AP = 0.0, LR = 0.0, DS = 0.0;
    for (int i = 0; i < 4; ++i) {
        int h = H0 >> i, w = W0 >> i;
        double nss = (double)B * 3.0 * (double)(h - 2) * (double)(w - 2);
        double nl1 = (double)B * 3.0 * (double)h * (double)w;
        double nd  = (double)B * (double)h * (double)w;
        AP += 0.85 * (acc[0 + i] / nss) + 0.15 * (acc[8 + i] / nl1);
        AP += 0.85 * (acc[4 + i] / nss) + 0.15 * (acc[12 + i] / nl1);
        LR += acc[16 + i] / nd + acc[20 + i] / nd;
        double sc = 1.0 / (double)(1 << i);
        DS += (acc[24 + i] / nd) * sc + (acc[28 + i] / nd) * sc;
    }
    AP *= 0.85;
    DS *= 0.1;
    double total = AP + LR + DS;
    out[0] = (float)total;
    out[1] = (float)AP;
    out[2] = (float)LR;
    out[3] = (float)DS;
}

// ---------------- host launch ----------------
static inline int grid_cap(long long blocks) {
    if (blocks > 2048) blocks = 2048;
    if (blocks < 1) blocks = 1;
    return (int)blocks;
}

extern "C" void kernel_launch(void* const* d_in, const int* in_sizes, int n_in,
                              void* d_out, int out_size, void* d_ws, size_t ws_size,
                              hipStream_t stream) {
    const int B = 32, H0 = 256, W0 = 512;
    const float* dsp[4];
    for (int i = 0; i < 4; ++i) dsp[i] = (const float*)d_in[i];
    const float* left  = (const float*)d_in[4];
    const float* right = (const float*)d_in[5];
    float* out = (float*)d_out;

    double* acc = (double*)d_ws;
    float* buf = (float*)((char*)d_ws + 256);

    const float* lp[4];
    const float* rp[4];
    float* lpm[4];
    float* rpm[4];
    lp[0] = left; rp[0] = right;
    float* cur = buf;
    for (int i = 1; i < 4; ++i) { lpm[i] = cur; cur += (long long)B * 3 * (H0 >> i) * (W0 >> i); }
    for (int i = 1; i < 4; ++i) { rpm[i] = cur; cur += (long long)B * 3 * (H0 >> i) * (W0 >> i); }
    for (int i = 1; i < 4; ++i) { lp[i] = lpm[i]; rp[i] = rpm[i]; }

    zero_acc_kernel<<<1, 64, 0, stream>>>(acc);

    for (int i = 1; i < 4; ++i) {
        int Hs = H0 >> (i - 1), Ws = W0 >> (i - 1);
        int Hd = H0 >> i, Wd = W0 >> i;
        long long tot = (long long)B * 3 * Hd * Wd;
        int g = (int)((tot + BDIM - 1) / BDIM);
        resize_kernel<<<g, BDIM, 0, stream>>>(lp[i - 1], lpm[i], B * 3, Hs, Ws, Hd, Wd);
        resize_kernel<<<g, BDIM, 0, stream>>>(rp[i - 1], rpm[i], B * 3, Hs, Ws, Hd, Wd);
    }

    for (int i = 0; i < 4; ++i) {
        int h = H0 >> i, w = W0 >> i;
        long long HW = (long long)h * w;
        long long dBS = 2 * HW;
        long long iBS = 3 * HW;

        int nTx = (w - 2 + TX - 1) / TX;
        int nTy = (h - 2 + TY - 1) / TY;
        int numTiles = B * nTx * nTy;
        int g = grid_cap(numTiles);

        fused_level_kernel<<<g, BDIM, 0, stream>>>(
            lp[i], rp[i], dsp[i], iBS, dBS, B, h, w, nTx, nTy, acc + i);
    }

    finalize_kernel<<<1, 1, 0, stream>>>(acc, out);
}

// Round 4
// 544.710 us; speedup vs baseline: 2.7306x; 1.1489x over previous
//
#include <hip/hip_runtime.h>

#define BDIM 256
#define SH 16

// ---------------- kernels ----------------
__global__ void zero_acc_kernel(double* acc) {
    if (threadIdx.x < 32) acc[threadIdx.x] = 0.0;
}

// generic align_corners bilinear resize; BC = B*C fused
__global__ void resize_kernel(const float* __restrict__ src, float* __restrict__ dst,
                              int BC, int Hs, int Ws, int Hd, int Wd) {
    long long idx = (long long)blockIdx.x * blockDim.x + threadIdx.x;
    long long total = (long long)BC * Hd * Wd;
    if (idx >= total) return;
    int i = (int)(idx % Wd);
    long long t = idx / Wd;
    int j = (int)(t % Hd);
    int bc = (int)(t / Hd);
    float stepy = (float)(Hs - 1) / (float)(Hd - 1);
    float stepx = (float)(Ws - 1) / (float)(Wd - 1);
    float y = j * stepy;
    float x = i * stepx;
    int y0 = (int)floorf(y);
    int y1 = min(y0 + 1, Hs - 1);
    int x0 = (int)floorf(x);
    int x1 = min(x0 + 1, Ws - 1);
    float wy = y - (float)y0;
    float wx = x - (float)x0;
    const float* s = src + (long long)bc * Hs * Ws;
    float t0 = s[(long long)y0 * Ws + x0] * (1.0f - wy) + s[(long long)y1 * Ws + x0] * wy;
    float t1 = s[(long long)y0 * Ws + x1] * (1.0f - wy) + s[(long long)y1 * Ws + x1] * wy;
    dst[idx] = t0 * (1.0f - wx) + t1 * wx;
}

__device__ __forceinline__ float ssim_term(float Sx, float Sy, float Sxx, float Syy, float Sxy) {
    const float C1v = 0.0001f;
    const float C2v = 0.0009f;
    float mux = Sx * (1.0f / 9.0f), muy = Sy * (1.0f / 9.0f);
    float sigx = Sxx * (1.0f / 9.0f) - mux * mux;
    float sigy = Syy * (1.0f / 9.0f) - muy * muy;
    float cov  = Sxy * (1.0f / 9.0f) - mux * muy;
    float num = (2.0f * mux * muy + C1v) * (2.0f * cov + C2v);
    float den = (mux * mux + muy * muy + C1v) * (sigx + sigy + C2v);
    float v = (1.0f - num / den) * 0.5f;
    return fminf(fmaxf(v, 0.0f), 1.0f);
}

// Barrier-free wave-marching level kernel.
// Each wave: one (side, b, row-strip, col-window) strip. 64 lanes = 64 columns
// (62 SSIM outputs). Marches rows top->bottom keeping 3-row column sums of the
// 5 SSIM stats in registers (pair-partial); 3-wide horizontal window sums via
// __shfl_down. L1/LR/smoothness fused into the same march.
// acc slot layout (accL = acc + level): ssim +0/+4(side), l1 +8/+12,
// lr +16/+20, ds +24/+28.
__global__ void __launch_bounds__(BDIM)
level_kernel(const float* __restrict__ lp, const float* __restrict__ rp,
             const float* __restrict__ dp, int B, int H, int W,
             int nCW, int nRS, double* __restrict__ accL) {
    const int lane = threadIdx.x & 63;
    const int wid  = threadIdx.x >> 6;
    const int wId  = blockIdx.x * (BDIM / 64) + wid;
    const int totalWork = 2 * B * nRS * nCW;
    const long long HW = (long long)H * W;
    const long long iBS = 3 * HW;
    const long long dBS = 2 * HW;
    const float Wm1f = (float)(W - 1);

    float f_ss = 0.f, f_l1 = 0.f, f_lr = 0.f, f_ds = 0.f;
    int side = 0;

    if (wId < totalWork) {
        int w = wId;
        const int cw = w % nCW; w /= nCW;
        const int rs = w % nRS; w /= nRS;
        const int b  = w % B;
        side = w / B;

        const int col = cw * 62 + lane;
        const bool colIn = col < W;
        const float fcol = (float)col;
        const float sgn = (side == 0) ? -1.0f : 1.0f;

        const float* xim = (side == 0 ? lp : rp) + (long long)b * iBS;  // image compared
        const float* sim = (side == 0 ? rp : lp) + (long long)b * iBS;  // warp source
        const float* dme = dp + (long long)b * dBS + (side == 0 ? 0 : HW);
        const float* dot = dp + (long long)b * dBS + (side == 0 ? HW : 0);

        const int r0 = rs * SH;
        const int r1 = min(r0 + SH, H);
        const int jend = min(r1 + 1, H - 1);

        const bool ownC = colIn && (lane < 62 || cw == nCW - 1);  // L1/LR/smooth owner
        const bool ownS = (lane < 62) && (col <= W - 3);          // SSIM owner

        float P[3][5], Ls[3][5];
#pragma unroll
        for (int c = 0; c < 3; ++c)
#pragma unroll
            for (int s = 0; s < 5; ++s) { P[c][s] = 0.f; Ls[c][s] = 0.f; }
        float pd = 0.f, px0 = 0.f, px1 = 0.f, px2 = 0.f;

        for (int j = r0; j <= jend; ++j) {
            const long long ro = (long long)j * W;
            const float* dmr = dme + ro;
            const float* dor = dot + ro;
            float d = colIn ? dmr[col] : 0.0f;
            float xq = fmaf(sgn * d, Wm1f, fcol);   // == ((gx+1)/2)*(W-1)
            float xf = floorf(xq);
            int   x0 = (int)xf;
            float w1 = xq - xf;
            float w0 = 1.0f - w1;
            bool v0 = (x0 >= 0) && (x0 < W);
            bool v1 = (x0 >= -1) && (x0 < W - 1);
            float wv = (v0 ? dor[x0] * w0 : 0.0f) + (v1 ? dor[x0 + 1] * w1 : 0.0f);

            float xv[3], yv[3];
#pragma unroll
            for (int c = 0; c < 3; ++c) {
                const float* xr = xim + (long long)c * HW + ro;
                const float* sr = sim + (long long)c * HW + ro;
                xv[c] = colIn ? xr[col] : 0.0f;
                yv[c] = (v0 ? sr[x0] * w0 : 0.0f) + (v1 ? sr[x0 + 1] * w1 : 0.0f);
            }

            const bool rowOwn = j < r1;
            if (ownC && rowOwn) {
                f_l1 += fabsf(xv[0] - yv[0]) + fabsf(xv[1] - yv[1]) + fabsf(xv[2] - yv[2]);
                f_lr += fabsf(d - wv);
            }

            // smoothness x-gradient (needs col+1 from lane+1)
            {
                float dn = __shfl_down(d, 1);
                float g = fabsf(xv[0] - __shfl_down(xv[0], 1))
                        + fabsf(xv[1] - __shfl_down(xv[1], 1))
                        + fabsf(xv[2] - __shfl_down(xv[2], 1));
                if (ownC && rowOwn && (col < W - 1))
                    f_ds += fabsf((d - dn) * __expf(-g * (1.0f / 3.0f)));
            }
            // smoothness y-gradient for previous row (prev regs vs current)
            if (ownC && (j > r0) && (j - 1 < r1)) {
                float g = fabsf(px0 - xv[0]) + fabsf(px1 - xv[1]) + fabsf(px2 - xv[2]);
                f_ds += fabsf((pd - d) * __expf(-g * (1.0f / 3.0f)));
            }
            pd = d; px0 = xv[0]; px1 = xv[1]; px2 = xv[2];

            const bool emit = (j >= r0 + 2);  // wave-uniform
#pragma unroll
            for (int c = 0; c < 3; ++c) {
                float cx = xv[c], cy = yv[c];
                float cxx = cx * cx, cyy = cy * cy, cxy = cx * cy;
                float Sx  = P[c][0] + cx;
                float Sy  = P[c][1] + cy;
                float Sxx = P[c][2] + cxx;
                float Syy = P[c][3] + cyy;
                float Sxy = P[c][4] + cxy;
                P[c][0] = Ls[c][0] + cx;  Ls[c][0] = cx;
                P[c][1] = Ls[c][1] + cy;  Ls[c][1] = cy;
                P[c][2] = Ls[c][2] + cxx; Ls[c][2] = cxx;
                P[c][3] = Ls[c][3] + cyy; Ls[c][3] = cyy;
                P[c][4] = Ls[c][4] + cxy; Ls[c][4] = cxy;
                if (emit) {
                    float Wx  = Sx  + __shfl_down(Sx, 1)  + __shfl_down(Sx, 2);
                    float Wy  = Sy  + __shfl_down(Sy, 1)  + __shfl_down(Sy, 2);
                    float Wxx = Sxx + __shfl_down(Sxx, 1) + __shfl_down(Sxx, 2);
                    float Wyy = Syy + __shfl_down(Syy, 1) + __shfl_down(Syy, 2);
                    float Wxy = Sxy + __shfl_down(Sxy, 1) + __shfl_down(Sxy, 2);
                    float term = ssim_term(Wx, Wy, Wxx, Wyy, Wxy);
                    f_ss += ownS ? term : 0.0f;
                }
            }
        }
    }

    // ---- reduction: wave shuffle -> LDS (8 slots) -> 8 atomics/block ----
    float v0 = f_ss, v1 = f_l1, v2 = f_lr, v3 = f_ds;
#pragma unroll
    for (int o = 32; o > 0; o >>= 1) {
        v0 += __shfl_down(v0, o);
        v1 += __shfl_down(v1, o);
        v2 += __shfl_down(v2, o);
        v3 += __shfl_down(v3, o);
    }
    __shared__ float red[BDIM / 64][8];
    if (lane == 0) {
#pragma unroll
        for (int s = 0; s < 8; ++s) red[wid][s] = 0.f;
        red[wid][side * 4 + 0] = v0;
        red[wid][side * 4 + 1] = v1;
        red[wid][side * 4 + 2] = v2;
        red[wid][side * 4 + 3] = v3;
    }
    __syncthreads();
    if (threadIdx.x < 8) {
        int t = threadIdx.x;
        double s = (double)red[0][t] + (double)red[1][t]
                 + (double)red[2][t] + (double)red[3][t];
        int sd = t >> 2, tm = t & 3;
        // term bases: ssim 0, l1 8, lr 16, ds 24; +4 for right side
        atomicAdd(accL + tm * 8 + sd * 4, s);
    }
}

__global__ void finalize_kernel(const double* __restrict__ acc, float* __restrict__ out) {
    const int B = 32, H0 = 256, W0 = 512;
    double AP = 0.0, LR = 0.0, DS = 0.0;
    for (int i = 0; i < 4; ++i) {
        int h = H0 >> i, w = W0 >> i;
        double nss = (double)B * 3.0 * (double)(h - 2) * (double)(w - 2);
        double nl1 = (double)B * 3.0 * (double)h * (double)w;
        double nd  = (double)B * (double)h * (double)w;
        AP += 0.85 * (acc[0 + i] / nss) + 0.15 * (acc[8 + i] / nl1);
        AP += 0.85 * (acc[4 + i] / nss) + 0.15 * (acc[12 + i] / nl1);
        LR += acc[16 + i] / nd + acc[20 + i] / nd;
        double sc = 1.0 / (double)(1 << i);
        DS += (acc[24 + i] / nd) * sc + (acc[28 + i] / nd) * sc;
    }
    AP *= 0.85;
    DS *= 0.1;
    double total = AP + LR + DS;
    out[0] = (float)total;
    out[1] = (float)AP;
    out[2] = (float)LR;
    out[3] = (float)DS;
}

// ---------------- host launch ----------------
extern "C" void kernel_launch(void* const* d_in, const int* in_sizes, int n_in,
                              void* d_out, int out_size, void* d_ws, size_t ws_size,
                              hipStream_t stream) {
    const int B = 32, H0 = 256, W0 = 512;
    const float* dsp[4];
    for (int i = 0; i < 4; ++i) dsp[i] = (const float*)d_in[i];
    const float* left  = (const float*)d_in[4];
    const float* right = (const float*)d_in[5];
    float* out = (float*)d_out;

    double* acc = (double*)d_ws;
    float* buf = (float*)((char*)d_ws + 256);

    const float* lp[4];
    const float* rp[4];
    float* lpm[4];
    float* rpm[4];
    lp[0] = left; rp[0] = right;
    float* cur = buf;
    for (int i = 1; i < 4; ++i) { lpm[i] = cur; cur += (long long)B * 3 * (H0 >> i) * (W0 >> i); }
    for (int i = 1; i < 4; ++i) { rpm[i] = cur; cur += (long long)B * 3 * (H0 >> i) * (W0 >> i); }
    for (int i = 1; i < 4; ++i) { lp[i] = lpm[i]; rp[i] = rpm[i]; }

    zero_acc_kernel<<<1, 64, 0, stream>>>(acc);

    for (int i = 1; i < 4; ++i) {
        int Hs = H0 >> (i - 1), Ws = W0 >> (i - 1);
        int Hd = H0 >> i, Wd = W0 >> i;
        long long tot = (long long)B * 3 * Hd * Wd;
        int g = (int)((tot + BDIM - 1) / BDIM);
        resize_kernel<<<g, BDIM, 0, stream>>>(lp[i - 1], lpm[i], B * 3, Hs, Ws, Hd, Wd);
        resize_kernel<<<g, BDIM, 0, stream>>>(rp[i - 1], rpm[i], B * 3, Hs, Ws, Hd, Wd);
    }

    for (int i = 0; i < 4; ++i) {
        int h = H0 >> i, w = W0 >> i;
        int nCW = (w - 2 + 61) / 62;
        int nRS = (h + SH - 1) / SH;
        int totalWork = 2 * B * nRS * nCW;
        int blocks = (totalWork + (BDIM / 64) - 1) / (BDIM / 64);
        level_kernel<<<blocks, BDIM, 0, stream>>>(
            lp[i], rp[i], dsp[i], B, h, w, nCW, nRS, acc + i);
    }

    finalize_kernel<<<1, 1, 0, stream>>>(acc, out);
}

// Round 5
// 301.657 us; speedup vs baseline: 4.9306x; 1.8057x over previous
//
#include <hip/hip_runtime.h>

#define BDIM 256
#define SH 16

struct LevelDesc {
    const float* lp; const float* rp; const float* dp;
    int H, W, nCW, nRS, nPerSide, waveBase;
};
struct AllParams { LevelDesc lv[4]; int totalWaves; };

// ---------------- kernels ----------------
__global__ void zero_acc_kernel(double* acc) {
    if (threadIdx.x < 32) acc[threadIdx.x] = 0.0;
}

// fused L+R align_corners bilinear resize
__global__ void resize2_kernel(const float* __restrict__ sL, const float* __restrict__ sR,
                               float* __restrict__ dL, float* __restrict__ dR,
                               int BC, int Hs, int Ws, int Hd, int Wd) {
    long long half = (long long)BC * Hd * Wd;
    long long idx = (long long)blockIdx.x * blockDim.x + threadIdx.x;
    if (idx >= 2 * half) return;
    const float* src = (idx < half) ? sL : sR;
    float* dst = (idx < half) ? dL : dR;
    long long id = (idx < half) ? idx : idx - half;
    int i = (int)(id % Wd);
    long long t = id / Wd;
    int j = (int)(t % Hd);
    int bc = (int)(t / Hd);
    float stepy = (float)(Hs - 1) / (float)(Hd - 1);
    float stepx = (float)(Ws - 1) / (float)(Wd - 1);
    float y = j * stepy;
    float x = i * stepx;
    int y0 = (int)floorf(y);
    int y1 = min(y0 + 1, Hs - 1);
    int x0 = (int)floorf(x);
    int x1 = min(x0 + 1, Ws - 1);
    float wy = y - (float)y0;
    float wx = x - (float)x0;
    const float* s = src + (long long)bc * Hs * Ws;
    float t0 = s[(long long)y0 * Ws + x0] * (1.0f - wy) + s[(long long)y1 * Ws + x0] * wy;
    float t1 = s[(long long)y0 * Ws + x1] * (1.0f - wy) + s[(long long)y1 * Ws + x1] * wy;
    dst[id] = t0 * (1.0f - wx) + t1 * wx;
}

__device__ __forceinline__ float ssim_term(float Sx, float Sy, float Sxx, float Syy, float Sxy) {
    const float C1v = 0.0001f;
    const float C2v = 0.0009f;
    float mux = Sx * (1.0f / 9.0f), muy = Sy * (1.0f / 9.0f);
    float sigx = Sxx * (1.0f / 9.0f) - mux * mux;
    float sigy = Syy * (1.0f / 9.0f) - muy * muy;
    float cov  = Sxy * (1.0f / 9.0f) - mux * muy;
    float num = (2.0f * mux * muy + C1v) * (2.0f * cov + C2v);
    float den = (mux * mux + muy * muy + C1v) * (sigx + sigy + C2v);
    float v = (1.0f - num * __builtin_amdgcn_rcpf(den)) * 0.5f;
    return fminf(fmaxf(v, 0.0f), 1.0f);
}

// All-level fused kernel. Each wave: one (level, side, b, row-strip, col-window).
// 2 px/lane: lane covers cols base+2*lane, base+2*lane+1 (window = 128 cols,
// 126 owned). Vertical-first separable SSIM (pair-partial column sums in regs),
// horizontal 3-window via 2 shuffles per stat producing BOTH outputs.
// acc layout: term base {ssim 0, l1 8, lr 16, ds 24} + side*4 + level.
__global__ void __launch_bounds__(BDIM)
mega_kernel(AllParams P, double* __restrict__ acc) {
    const int lane = threadIdx.x & 63;
    const int wid  = threadIdx.x >> 6;
    const int wId  = blockIdx.x * (BDIM / 64) + wid;
    const int w = min(wId, P.totalWaves - 1);

    int level = 0;
    if (w >= P.lv[1].waveBase) level = 1;
    if (w >= P.lv[2].waveBase) level = 2;
    if (w >= P.lv[3].waveBase) level = 3;
    LevelDesc L;
    if (level == 0) L = P.lv[0];
    else if (level == 1) L = P.lv[1];
    else if (level == 2) L = P.lv[2];
    else L = P.lv[3];

    int rel = w - L.waveBase;
    const int side = (rel >= L.nPerSide) ? 1 : 0;
    rel -= side * L.nPerSide;
    const int cw = rel % L.nCW; rel /= L.nCW;
    const int rs = rel % L.nRS;
    const int b  = rel / L.nRS;

    const int H = L.H, W = L.W;
    const long long HW = (long long)H * W;
    const float Wm1f = (float)(W - 1);
    const float sgn = side ? 1.0f : -1.0f;

    const float* xim = (side ? L.rp : L.lp) + (long long)b * 3 * HW;
    const float* sim = (side ? L.lp : L.rp) + (long long)b * 3 * HW;
    const float* dme = L.dp + (long long)b * 2 * HW + (side ? HW : 0);
    const float* dot = L.dp + (long long)b * 2 * HW + (side ? 0 : HW);

    const int base = cw * 126;
    const int c0 = base + 2 * lane;
    const int c1 = c0 + 1;
    const bool in0 = c0 < W, in1 = c1 < W;
    const int cc = min(c0, W - 2) >> 1;          // clamped float2 index
    const float fc0 = (float)c0, fc1 = (float)c1;

    const bool lastW = (cw == L.nCW - 1);
    const bool own0 = in0 && (c0 < base + 126 || lastW);
    const bool own1 = in1 && (c1 < base + 126 || lastW);
    const bool ownS0 = own0 && (c0 <= W - 3);
    const bool ownS1 = own1 && (c1 <= W - 3);

    const int r0 = rs * SH;
    const int r1 = min(r0 + SH, H);
    const int jend = min(r1 + 1, H - 1);

    float Pst[3][5][2], Lst[3][5][2];
#pragma unroll
    for (int c = 0; c < 3; ++c)
#pragma unroll
        for (int s = 0; s < 5; ++s) { Pst[c][s][0] = 0.f; Pst[c][s][1] = 0.f;
                                      Lst[c][s][0] = 0.f; Lst[c][s][1] = 0.f; }
    float pd0 = 0.f, pd1 = 0.f;
    float pxv[3][2] = {{0.f,0.f},{0.f,0.f},{0.f,0.f}};

    float f_ss = 0.f, f_l1 = 0.f, f_lr = 0.f, f_ds = 0.f;

    for (int j = r0; j <= jend; ++j) {
        const long long ro = (long long)j * W;
        float2 dpair = ((const float2*)(dme + ro))[cc];
        float d0 = dpair.x, d1 = dpair.y;

        float xq0 = fmaf(sgn * d0, Wm1f, fc0);
        float xq1 = fmaf(sgn * d1, Wm1f, fc1);
        float xf0 = floorf(xq0), xf1 = floorf(xq1);
        int g0 = (int)xf0, g1 = (int)xf1;
        float t0 = xq0 - xf0, t1 = xq1 - xf1;
        float w00 = (g0 >= 0 && g0 < W)         ? 1.0f - t0 : 0.0f;
        float w01 = (g0 >= -1 && g0 < W - 1)    ? t0        : 0.0f;
        float w10 = (g1 >= 0 && g1 < W)         ? 1.0f - t1 : 0.0f;
        float w11 = (g1 >= -1 && g1 < W - 1)    ? t1        : 0.0f;
        int a0 = min(max(g0, 0), W - 1);
        int a1 = min(max(g0 + 1, 0), W - 1);
        int b0 = min(max(g1, 0), W - 1);
        int b1 = min(max(g1 + 1, 0), W - 1);

        const float* dor = dot + ro;
        float wv0 = dor[a0] * w00 + dor[a1] * w01;
        float wv1 = dor[b0] * w10 + dor[b1] * w11;

        float xv[3][2], yv[3][2];
#pragma unroll
        for (int c = 0; c < 3; ++c) {
            const float* xr = xim + (long long)c * HW + ro;
            const float* sr = sim + (long long)c * HW + ro;
            float2 xp2 = ((const float2*)xr)[cc];
            xv[c][0] = in0 ? xp2.x : 0.f;
            xv[c][1] = in1 ? xp2.y : 0.f;
            yv[c][0] = sr[a0] * w00 + sr[a1] * w01;
            yv[c][1] = sr[b0] * w10 + sr[b1] * w11;
            if (!in0) yv[c][0] = 0.f;
            if (!in1) yv[c][1] = 0.f;
        }

        const bool rowOwn = j < r1;
        if (rowOwn) {
            if (own0) {
                f_l1 += fabsf(xv[0][0] - yv[0][0]) + fabsf(xv[1][0] - yv[1][0]) + fabsf(xv[2][0] - yv[2][0]);
                f_lr += fabsf(d0 - wv0);
            }
            if (own1) {
                f_l1 += fabsf(xv[0][1] - yv[0][1]) + fabsf(xv[1][1] - yv[1][1]) + fabsf(xv[2][1] - yv[2][1]);
                f_lr += fabsf(d1 - wv1);
            }
        }

        // smoothness x-gradients
        {
            float dn  = __shfl_down(d0, 1);
            float xn0 = __shfl_down(xv[0][0], 1);
            float xn1 = __shfl_down(xv[1][0], 1);
            float xn2 = __shfl_down(xv[2][0], 1);
            if (rowOwn) {
                if (own0 && c0 < W - 1) {
                    float g = fabsf(xv[0][0] - xv[0][1]) + fabsf(xv[1][0] - xv[1][1]) + fabsf(xv[2][0] - xv[2][1]);
                    f_ds += fabsf((d0 - d1) * __expf(-g * (1.0f / 3.0f)));
                }
                if (own1 && c1 < W - 1) {
                    float g = fabsf(xv[0][1] - xn0) + fabsf(xv[1][1] - xn1) + fabsf(xv[2][1] - xn2);
                    f_ds += fabsf((d1 - dn) * __expf(-g * (1.0f / 3.0f)));
                }
            }
        }
        // smoothness y-gradients (prev row in regs)
        if (j > r0 && (j - 1) < r1) {
            if (own0) {
                float g = fabsf(pxv[0][0] - xv[0][0]) + fabsf(pxv[1][0] - xv[1][0]) + fabsf(pxv[2][0] - xv[2][0]);
                f_ds += fabsf((pd0 - d0) * __expf(-g * (1.0f / 3.0f)));
            }
            if (own1) {
                float g = fabsf(pxv[0][1] - xv[0][1]) + fabsf(pxv[1][1] - xv[1][1]) + fabsf(pxv[2][1] - xv[2][1]);
                f_ds += fabsf((pd1 - d1) * __expf(-g * (1.0f / 3.0f)));
            }
        }
        pd0 = d0; pd1 = d1;
#pragma unroll
        for (int c = 0; c < 3; ++c) { pxv[c][0] = xv[c][0]; pxv[c][1] = xv[c][1]; }

        const bool emit = (j >= r0 + 2);  // wave-uniform
#pragma unroll
        for (int c = 0; c < 3; ++c) {
            float cs[5][2];
#pragma unroll
            for (int p = 0; p < 2; ++p) {
                float cx = xv[c][p], cy = yv[c][p];
                float v5[5] = {cx, cy, cx * cx, cy * cy, cx * cy};
#pragma unroll
                for (int s = 0; s < 5; ++s) {
                    cs[s][p] = Pst[c][s][p] + v5[s];
                    Pst[c][s][p] = Lst[c][s][p] + v5[s];
                    Lst[c][s][p] = v5[s];
                }
            }
            if (emit) {
                float w0s[5], w1s[5];
#pragma unroll
                for (int s = 0; s < 5; ++s) {
                    float n0 = __shfl_down(cs[s][0], 1);
                    float n1 = __shfl_down(cs[s][1], 1);
                    w0s[s] = cs[s][0] + cs[s][1] + n0;
                    w1s[s] = cs[s][1] + n0 + n1;
                }
                float ts0 = ssim_term(w0s[0], w0s[1], w0s[2], w0s[3], w0s[4]);
                float ts1 = ssim_term(w1s[0], w1s[1], w1s[2], w1s[3], w1s[4]);
                f_ss += (ownS0 ? ts0 : 0.f) + (ownS1 ? ts1 : 0.f);
            }
        }
    }

    // ---- reduction ----
#pragma unroll
    for (int o = 32; o > 0; o >>= 1) {
        f_ss += __shfl_down(f_ss, o);
        f_l1 += __shfl_down(f_l1, o);
        f_lr += __shfl_down(f_lr, o);
        f_ds += __shfl_down(f_ds, o);
    }
    __shared__ float red[BDIM / 64][4];
    __shared__ int meta[2];
    if (threadIdx.x == 0) { meta[0] = level; meta[1] = side; }
    if (lane == 0) {
        red[wid][0] = f_ss; red[wid][1] = f_l1;
        red[wid][2] = f_lr; red[wid][3] = f_ds;
    }
    __syncthreads();
    if (threadIdx.x < 4) {
        int t = threadIdx.x;
        double s = (double)red[0][t] + (double)red[1][t]
                 + (double)red[2][t] + (double)red[3][t];
        atomicAdd(acc + t * 8 + meta[1] * 4 + meta[0], s);
    }
}

__global__ void finalize_kernel(const double* __restrict__ acc, float* __restrict__ out) {
    const int B = 32, H0 = 256, W0 = 512;
    double AP = 0.0, LR = 0.0, DS = 0.0;
    for (int i = 0; i < 4; ++i) {
        int h = H0 >> i, w = W0 >> i;
        double nss = (double)B * 3.0 * (double)(h - 2) * (double)(w - 2);
        double nl1 = (double)B * 3.0 * (double)h * (double)w;
        double nd  = (double)B * (double)h * (double)w;
        AP += 0.85 * (acc[0 + i] / nss) + 0.15 * (acc[8 + i] / nl1);
        AP += 0.85 * (acc[4 + i] / nss) + 0.15 * (acc[12 + i] / nl1);
        LR += acc[16 + i] / nd + acc[20 + i] / nd;
        double sc = 1.0 / (double)(1 << i);
        DS += (acc[24 + i] / nd) * sc + (acc[28 + i] / nd) * sc;
    }
    AP *= 0.85;
    DS *= 0.1;
    double total = AP + LR + DS;
    out[0] = (float)total;
    out[1] = (float)AP;
    out[2] = (float)LR;
    out[3] = (float)DS;
}

// ---------------- host launch ----------------
extern "C" void kernel_launch(void* const* d_in, const int* in_sizes, int n_in,
                              void* d_out, int out_size, void* d_ws, size_t ws_size,
                              hipStream_t stream) {
    const int B = 32, H0 = 256, W0 = 512;
    const float* dsp[4];
    for (int i = 0; i < 4; ++i) dsp[i] = (const float*)d_in[i];
    const float* left  = (const float*)d_in[4];
    const float* right = (const float*)d_in[5];
    float* out = (float*)d_out;

    double* acc = (double*)d_ws;
    float* buf = (float*)((char*)d_ws + 256);

    const float* lp[4];
    const float* rp[4];
    float* lpm[4];
    float* rpm[4];
    lp[0] = left; rp[0] = right;
    float* cur = buf;
    for (int i = 1; i < 4; ++i) { lpm[i] = cur; cur += (long long)B * 3 * (H0 >> i) * (W0 >> i); }
    for (int i = 1; i < 4; ++i) { rpm[i] = cur; cur += (long long)B * 3 * (H0 >> i) * (W0 >> i); }
    for (int i = 1; i < 4; ++i) { lp[i] = lpm[i]; rp[i] = rpm[i]; }

    zero_acc_kernel<<<1, 64, 0, stream>>>(acc);

    for (int i = 1; i < 4; ++i) {
        int Hs = H0 >> (i - 1), Ws = W0 >> (i - 1);
        int Hd = H0 >> i, Wd = W0 >> i;
        long long half = (long long)B * 3 * Hd * Wd;
        int g = (int)((2 * half + BDIM - 1) / BDIM);
        resize2_kernel<<<g, BDIM, 0, stream>>>(
            lp[i - 1], rp[i - 1], lpm[i], rpm[i], B * 3, Hs, Ws, Hd, Wd);
    }

    AllParams P;
    int wb = 0;
    for (int i = 0; i < 4; ++i) {
        int h = H0 >> i, w = W0 >> i;
        LevelDesc& L = P.lv[i];
        L.lp = lp[i]; L.rp = rp[i]; L.dp = dsp[i];
        L.H = h; L.W = w;
        L.nCW = (w - 2 + 125) / 126;
        L.nRS = h / SH;
        L.nPerSide = B * L.nRS * L.nCW;
        L.waveBase = wb;
        wb += 2 * L.nPerSide;
    }
    P.totalWaves = wb;
    int blocks = (wb + (BDIM / 64) - 1) / (BDIM / 64);
    mega_kernel<<<blocks, BDIM, 0, stream>>>(P, acc);

    finalize_kernel<<<1, 1, 0, stream>>>(acc, out);
}